// Round 1
// baseline (397.289 us; speedup 1.0000x reference)
//
#include <hip/hip_runtime.h>
#include <math.h>

#define BATCH 16384
#define INFEAT 256
#define HID 128
#define NQ 10
#define NL 4
#define NSTATE 1024

// ---------------- Kernel A: angles = tanh(relu(x@W1^T+b1)@W2^T+b2) ----------------
__global__ __launch_bounds__(256) void angles_kernel(
    const float* __restrict__ x, const float* __restrict__ W1,
    const float* __restrict__ b1, const float* __restrict__ W2,
    const float* __restrict__ b2, float* __restrict__ angles)
{
    __shared__ float smem[9632];
    float* xs = smem;                 // 64 x 36 (row-major x tile, padded)
    float* wt = smem + 64 * 36;       // 32 x 132 (k-major W1 tile, padded)
    const int t = threadIdx.x;
    const int tr = t & 15, tc = t >> 4;
    const int row0 = blockIdx.x * 64;

    float b1v[8];
#pragma unroll
    for (int j = 0; j < 8; ++j) b1v[j] = b1[tc * 8 + j];

    float acc[4][8];
#pragma unroll
    for (int i = 0; i < 4; ++i)
#pragma unroll
        for (int j = 0; j < 8; ++j) acc[i][j] = 0.f;

    for (int k0 = 0; k0 < INFEAT; k0 += 32) {
        __syncthreads();
        // stage x tile: 64 rows x 32 k  (512 float4)
        for (int f = t; f < 512; f += 256) {
            int i = f >> 3, j4 = f & 7;
            float4 v = *(const float4*)(x + (size_t)(row0 + i) * INFEAT + k0 + j4 * 4);
            *(float4*)(xs + i * 36 + j4 * 4) = v;
        }
        // stage W1 tile transposed to k-major: 128 cols x 32 k (1024 float4 scattered)
        for (int f = t; f < 1024; f += 256) {
            int c = f >> 3, j4 = f & 7;
            float4 v = *(const float4*)(W1 + (size_t)c * INFEAT + k0 + j4 * 4);
            wt[(j4 * 4 + 0) * 132 + c] = v.x;
            wt[(j4 * 4 + 1) * 132 + c] = v.y;
            wt[(j4 * 4 + 2) * 132 + c] = v.z;
            wt[(j4 * 4 + 3) * 132 + c] = v.w;
        }
        __syncthreads();
#pragma unroll 4
        for (int k = 0; k < 32; ++k) {
            float xv[4];
#pragma unroll
            for (int i = 0; i < 4; ++i) xv[i] = xs[(tr * 4 + i) * 36 + k];
            float4 wa = *(const float4*)(wt + k * 132 + tc * 8);
            float4 wb = *(const float4*)(wt + k * 132 + tc * 8 + 4);
            float wv[8] = {wa.x, wa.y, wa.z, wa.w, wb.x, wb.y, wb.z, wb.w};
#pragma unroll
            for (int i = 0; i < 4; ++i)
#pragma unroll
                for (int j = 0; j < 8; ++j)
                    acc[i][j] = fmaf(xv[i], wv[j], acc[i][j]);
        }
    }
    __syncthreads();
    // stage 2: h tile -> LDS, then angles = tanh(h@W2^T + b2)
    float* hbuf = smem;            // 64 x 130
    float* w2s  = smem + 8320;     // 10 x 130
    float* b2s  = smem + 9620;     // 10
    for (int f = t; f < HID * NQ; f += 256) {
        int k = f >> 7, c = f & 127;
        w2s[k * 130 + c] = W2[f];
    }
    if (t < NQ) b2s[t] = b2[t];
#pragma unroll
    for (int i = 0; i < 4; ++i)
#pragma unroll
        for (int j = 0; j < 8; ++j)
            hbuf[(tr * 4 + i) * 130 + tc * 8 + j] = fmaxf(acc[i][j] + b1v[j], 0.f);
    __syncthreads();
    for (int f = t; f < 64 * NQ; f += 256) {
        int row = f / 10;
        int k = f - row * 10;
        float s = b2s[k];
        const float* hr = hbuf + row * 130;
        const float* wr = w2s + k * 130;
#pragma unroll 8
        for (int c = 0; c < HID; ++c) s = fmaf(hr[c], wr[c], s);
        angles[(size_t)(row0 + row) * NQ + k] = tanhf(s);
    }
}

// ---------------- Kernel B: circuit + head, one wave per batch row ----------------
// State layout: index s = r*64 + lane  (r = 4 high bits -> qubits 0..3, lane bits -> qubits 4..9)
// Qubit w occupies bit (9-w) of s.
__global__ __launch_bounds__(256) void circuit_kernel(
    const float* __restrict__ angles, const float* __restrict__ qw,
    const float* __restrict__ W3, const float* __restrict__ b3,
    const float* __restrict__ W4, const float* __restrict__ b4,
    float* __restrict__ out)
{
    __shared__ float gate[NL * NQ][8];
    __shared__ unsigned short perm[NL][NSTATE];
    __shared__ float w3s[HID * 11];
    __shared__ float b3s[HID], w4s[HID];
    __shared__ float b4s;
    __shared__ float2 st[4][NSTATE];

    const int t = threadIdx.x;
    // Rot gate table (shared across batch): 40 gates x (m00,m01,m10,m11) complex
    if (t < NL * NQ) {
        float phi = qw[t * 3 + 0], th = qw[t * 3 + 1], om = qw[t * 3 + 2];
        float c = __cosf(th * 0.5f), s = __sinf(th * 0.5f);
        float a = 0.5f * (phi + om), b = 0.5f * (phi - om);
        float ca = __cosf(a), sa = __sinf(a);
        float cb = __cosf(b), sb = __sinf(b);
        gate[t][0] = ca * c;  gate[t][1] = -sa * c;   // m00
        gate[t][2] = -cb * s; gate[t][3] = -sb * s;   // m01
        gate[t][4] = cb * s;  gate[t][5] = -sb * s;   // m10
        gate[t][6] = ca * c;  gate[t][7] = sa * c;    // m11
    }
    for (int f = t; f < HID * NQ; f += 256) {
        int c = f / NQ, k = f - c * NQ;
        w3s[c * 11 + k] = W3[f];
    }
    if (t < HID) { b3s[t] = b3[t]; w4s[t] = W4[t]; }
    if (t == 0) b4s = b4[0];
    // CNOT-ring permutation tables (GF(2)-linear, same for all rows)
    for (int f = t; f < NL * NSTATE; f += 256) {
        int l = f >> 10, s = f & (NSTATE - 1);
        int rs = (l % (NQ - 1)) + 1;
        int idx = s;
        for (int i = NQ - 1; i >= 0; --i) {
            int tq = (i + rs) % NQ;
            int bc = NQ - 1 - i, bt = NQ - 1 - tq;
            idx ^= ((idx >> bc) & 1) << bt;
        }
        perm[l][s] = (unsigned short)idx;
    }
    __syncthreads();

    const int wid = t >> 6, lane = t & 63;
    const int row = blockIdx.x * 4 + wid;

    float cth[NQ], sth[NQ];
#pragma unroll
    for (int w = 0; w < NQ; ++w) {
        float th = angles[(size_t)row * NQ + w] * 0.5f;
        cth[w] = __cosf(th); sth[w] = __sinf(th);
    }

    // RY ladder on |0..0> is a product state: amp(s) = prod_w (bit? sin : cos)
    float fl = 1.f;
#pragma unroll
    for (int w = 4; w < 10; ++w)
        fl *= ((lane >> (9 - w)) & 1) ? sth[w] : cth[w];
    float are[16], aim[16];
#pragma unroll
    for (int r = 0; r < 16; ++r) {
        float g = fl;
#pragma unroll
        for (int w = 0; w < 4; ++w)
            g *= ((r >> (3 - w)) & 1) ? sth[w] : cth[w];
        are[r] = g; aim[r] = 0.f;
    }

    float2* smy = st[wid];
#pragma unroll 1
    for (int l = 0; l < NL; ++l) {
        const int gbase = l * NQ;
        // local-bit Rot gates (qubits 0..3, bit 3-w of r)
#pragma unroll
        for (int w = 0; w < 4; ++w) {
            const float* g = gate[gbase + w];
            float m00r = g[0], m00i = g[1], m01r = g[2], m01i = g[3];
            float m10r = g[4], m10i = g[5], m11r = g[6], m11i = g[7];
            const int mask = 1 << (3 - w);
#pragma unroll
            for (int r0 = 0; r0 < 16; ++r0) {
                if (r0 & mask) continue;
                const int r1 = r0 | mask;
                float a0r = are[r0], a0i = aim[r0], a1r = are[r1], a1i = aim[r1];
                are[r0] = m00r * a0r - m00i * a0i + m01r * a1r - m01i * a1i;
                aim[r0] = m00r * a0i + m00i * a0r + m01r * a1i + m01i * a1r;
                are[r1] = m10r * a0r - m10i * a0i + m11r * a1r - m11i * a1i;
                aim[r1] = m10r * a0i + m10i * a0r + m11r * a1i + m11i * a1r;
            }
        }
        // lane-bit Rot gates (qubits 4..9, lane bit 9-w) via shfl_xor butterflies
#pragma unroll
        for (int w = 4; w < 10; ++w) {
            const float* g = gate[gbase + w];
            const int lb = 9 - w;
            const int side = (lane >> lb) & 1;
            float cmr = side ? g[6] : g[0];
            float cmi = side ? g[7] : g[1];
            float cpr = side ? g[4] : g[2];
            float cpi = side ? g[5] : g[3];
#pragma unroll
            for (int r = 0; r < 16; ++r) {
                float pr = __shfl_xor(are[r], 1 << lb, 64);
                float pi = __shfl_xor(aim[r], 1 << lb, 64);
                float nr = cmr * are[r] - cmi * aim[r] + cpr * pr - cpi * pi;
                float ni = cmr * aim[r] + cmi * are[r] + cpr * pi + cpi * pr;
                are[r] = nr; aim[r] = ni;
            }
        }
        // CNOT ring: LDS round-trip through precomputed permutation (wave-private region)
#pragma unroll
        for (int r = 0; r < 16; ++r)
            smy[r * 64 + lane] = make_float2(are[r], aim[r]);
        __syncthreads();
#pragma unroll
        for (int r = 0; r < 16; ++r) {
            float2 v = smy[perm[l][r * 64 + lane]];
            are[r] = v.x; aim[r] = v.y;
        }
        __syncthreads();
    }

    // Z expectations: e[w] = sum_s |amp|^2 * (1-2*bit_{9-w}(s))
    float p[16], ptot = 0.f;
#pragma unroll
    for (int r = 0; r < 16; ++r) { p[r] = are[r] * are[r] + aim[r] * aim[r]; ptot += p[r]; }
    float e[NQ];
#pragma unroll
    for (int w = 0; w < 4; ++w) {
        float ss = 0.f;
        const int mask = 1 << (3 - w);
#pragma unroll
        for (int r = 0; r < 16; ++r) if (r & mask) ss += p[r];
        e[w] = ptot - 2.f * ss;
    }
#pragma unroll
    for (int w = 4; w < 10; ++w)
        e[w] = ((lane >> (9 - w)) & 1) ? -ptot : ptot;
#pragma unroll
    for (int off = 1; off < 64; off <<= 1) {
#pragma unroll
        for (int w = 0; w < NQ; ++w) e[w] += __shfl_xor(e[w], off, 64);
    }

    // head: out = relu(q@W3^T+b3) @ W4^T + b4   (2 columns per lane + butterfly)
    float accv = 0.f;
#pragma unroll
    for (int j = 0; j < 2; ++j) {
        int c = lane + 64 * j;
        float d = b3s[c];
#pragma unroll
        for (int k = 0; k < NQ; ++k) d = fmaf(w3s[c * 11 + k], e[k], d);
        d = fmaxf(d, 0.f);
        accv = fmaf(d, w4s[c], accv);
    }
#pragma unroll
    for (int off = 1; off < 64; off <<= 1) accv += __shfl_xor(accv, off, 64);
    if (lane == 0) out[row] = accv + b4s;
}

extern "C" void kernel_launch(void* const* d_in, const int* in_sizes, int n_in,
                              void* d_out, int out_size, void* d_ws, size_t ws_size,
                              hipStream_t stream) {
    const float* x  = (const float*)d_in[0];
    const float* W1 = (const float*)d_in[1];
    const float* b1 = (const float*)d_in[2];
    const float* W2 = (const float*)d_in[3];
    const float* b2 = (const float*)d_in[4];
    const float* qw = (const float*)d_in[5];
    const float* W3 = (const float*)d_in[6];
    const float* b3 = (const float*)d_in[7];
    const float* W4 = (const float*)d_in[8];
    const float* b4 = (const float*)d_in[9];
    float* angles = (float*)d_ws;          // 16384 x 10 fp32 scratch
    float* out = (float*)d_out;

    angles_kernel<<<BATCH / 64, 256, 0, stream>>>(x, W1, b1, W2, b2, angles);
    circuit_kernel<<<BATCH / 4, 256, 0, stream>>>(angles, qw, W3, b3, W4, b4, out);
}

// Round 2
// 309.141 us; speedup vs baseline: 1.2851x; 1.2851x over previous
//
#include <hip/hip_runtime.h>
#include <math.h>

#define BATCH 16384
#define INFEAT 256
#define HID 128
#define NQ 10
#define NL 4
#define NSTATE 1024

// ---------------- Kernel A: angles = tanh(relu(x@W1^T+b1)@W2^T+b2) ----------------
__global__ __launch_bounds__(256) void angles_kernel(
    const float* __restrict__ x, const float* __restrict__ W1,
    const float* __restrict__ b1, const float* __restrict__ W2,
    const float* __restrict__ b2, float* __restrict__ angles)
{
    __shared__ float smem[9632];
    float* xs = smem;                 // 64 x 36 (row-major x tile, padded)
    float* wt = smem + 64 * 36;       // 32 x 132 (k-major W1 tile, padded)
    const int t = threadIdx.x;
    const int tr = t & 15, tc = t >> 4;
    const int row0 = blockIdx.x * 64;

    float b1v[8];
#pragma unroll
    for (int j = 0; j < 8; ++j) b1v[j] = b1[tc * 8 + j];

    float acc[4][8];
#pragma unroll
    for (int i = 0; i < 4; ++i)
#pragma unroll
        for (int j = 0; j < 8; ++j) acc[i][j] = 0.f;

    for (int k0 = 0; k0 < INFEAT; k0 += 32) {
        __syncthreads();
        // stage x tile: 64 rows x 32 k  (512 float4)
        for (int f = t; f < 512; f += 256) {
            int i = f >> 3, j4 = f & 7;
            float4 v = *(const float4*)(x + (size_t)(row0 + i) * INFEAT + k0 + j4 * 4);
            *(float4*)(xs + i * 36 + j4 * 4) = v;
        }
        // stage W1 tile transposed to k-major: 128 cols x 32 k (1024 float4 scattered)
        for (int f = t; f < 1024; f += 256) {
            int c = f >> 3, j4 = f & 7;
            float4 v = *(const float4*)(W1 + (size_t)c * INFEAT + k0 + j4 * 4);
            wt[(j4 * 4 + 0) * 132 + c] = v.x;
            wt[(j4 * 4 + 1) * 132 + c] = v.y;
            wt[(j4 * 4 + 2) * 132 + c] = v.z;
            wt[(j4 * 4 + 3) * 132 + c] = v.w;
        }
        __syncthreads();
#pragma unroll 4
        for (int k = 0; k < 32; ++k) {
            float xv[4];
#pragma unroll
            for (int i = 0; i < 4; ++i) xv[i] = xs[(tr * 4 + i) * 36 + k];
            float4 wa = *(const float4*)(wt + k * 132 + tc * 8);
            float4 wb = *(const float4*)(wt + k * 132 + tc * 8 + 4);
            float wv[8] = {wa.x, wa.y, wa.z, wa.w, wb.x, wb.y, wb.z, wb.w};
#pragma unroll
            for (int i = 0; i < 4; ++i)
#pragma unroll
                for (int j = 0; j < 8; ++j)
                    acc[i][j] = fmaf(xv[i], wv[j], acc[i][j]);
        }
    }
    __syncthreads();
    // stage 2: h tile -> LDS, then angles = tanh(h@W2^T + b2)
    float* hbuf = smem;            // 64 x 130
    float* w2s  = smem + 8320;     // 10 x 130
    float* b2s  = smem + 9620;     // 10
    for (int f = t; f < HID * NQ; f += 256) {
        int k = f >> 7, c = f & 127;
        w2s[k * 130 + c] = W2[f];
    }
    if (t < NQ) b2s[t] = b2[t];
#pragma unroll
    for (int i = 0; i < 4; ++i)
#pragma unroll
        for (int j = 0; j < 8; ++j)
            hbuf[(tr * 4 + i) * 130 + tc * 8 + j] = fmaxf(acc[i][j] + b1v[j], 0.f);
    __syncthreads();
    for (int f = t; f < 64 * NQ; f += 256) {
        int row = f / 10;
        int k = f - row * 10;
        float s = b2s[k];
        const float* hr = hbuf + row * 130;
        const float* wr = w2s + k * 130;
#pragma unroll 8
        for (int c = 0; c < HID; ++c) s = fmaf(hr[c], wr[c], s);
        angles[(size_t)(row0 + row) * NQ + k] = tanhf(s);
    }
}

// ---------------- Kernel B: circuit + head, one wave per batch row ----------------
// State layout: index s = r*64 + lane.  Qubit w occupies bit (9-w) of s:
//   qubits 0..3 -> register-index bits (r bit 3-w), qubits 4..9 -> lane bits (lane bit 9-w).
// CNOT ring (shift rs) decomposes per layer into runs RR* RL* LL* LR* over
// (reg-bit, lane-bit) categories; all applied in-register (no LDS state buffer,
// no barriers in the main loop).
__global__ __launch_bounds__(256) void circuit_kernel(
    const float* __restrict__ angles, const float* __restrict__ qw,
    const float* __restrict__ W3, const float* __restrict__ b3,
    const float* __restrict__ W4, const float* __restrict__ b4,
    float* __restrict__ out)
{
    __shared__ float gate[NL * NQ][8];
    __shared__ float w3s[HID * 11];
    __shared__ float b3s[HID], w4s[HID];
    __shared__ float b4s;

    const int t = threadIdx.x;
    // Rot gate table (shared across batch): 40 gates x (m00,m01,m10,m11) complex
    if (t < NL * NQ) {
        float phi = qw[t * 3 + 0], th = qw[t * 3 + 1], om = qw[t * 3 + 2];
        float c = __cosf(th * 0.5f), s = __sinf(th * 0.5f);
        float a = 0.5f * (phi + om), b = 0.5f * (phi - om);
        float ca = __cosf(a), sa = __sinf(a);
        float cb = __cosf(b), sb = __sinf(b);
        gate[t][0] = ca * c;  gate[t][1] = -sa * c;   // m00
        gate[t][2] = -cb * s; gate[t][3] = -sb * s;   // m01
        gate[t][4] = cb * s;  gate[t][5] = -sb * s;   // m10
        gate[t][6] = ca * c;  gate[t][7] = sa * c;    // m11
    }
    for (int f = t; f < HID * NQ; f += 256) {
        int c = f / NQ, k = f - c * NQ;
        w3s[c * 11 + k] = W3[f];
    }
    if (t < HID) { b3s[t] = b3[t]; w4s[t] = W4[t]; }
    if (t == 0) b4s = b4[0];
    __syncthreads();

    const int wid = t >> 6, lane = t & 63;
    const int row = blockIdx.x * 4 + wid;

    float cth[NQ], sth[NQ];
#pragma unroll
    for (int w = 0; w < NQ; ++w) {
        float th = angles[(size_t)row * NQ + w] * 0.5f;
        cth[w] = __cosf(th); sth[w] = __sinf(th);
    }

    // RY ladder on |0..0> is a product state: amp(s) = prod_w (bit? sin : cos)
    float fl = 1.f;
#pragma unroll
    for (int w = 4; w < 10; ++w)
        fl *= ((lane >> (9 - w)) & 1) ? sth[w] : cth[w];
    float are[16], aim[16];
#pragma unroll
    for (int r = 0; r < 16; ++r) {
        float g = fl;
#pragma unroll
        for (int w = 0; w < 4; ++w)
            g *= ((r >> (3 - w)) & 1) ? sth[w] : cth[w];
        are[r] = g; aim[r] = 0.f;
    }

#pragma unroll
    for (int l = 0; l < NL; ++l) {
        const int gbase = l * NQ;
        const int rs = l + 1;   // l % (NQ-1) + 1
        // local-bit Rot gates (qubits 0..3, bit 3-w of r)
#pragma unroll
        for (int w = 0; w < 4; ++w) {
            const float* g = gate[gbase + w];
            float m00r = g[0], m00i = g[1], m01r = g[2], m01i = g[3];
            float m10r = g[4], m10i = g[5], m11r = g[6], m11i = g[7];
            const int mask = 1 << (3 - w);
#pragma unroll
            for (int r0 = 0; r0 < 16; ++r0) {
                if (r0 & mask) continue;
                const int r1 = r0 | mask;
                float a0r = are[r0], a0i = aim[r0], a1r = are[r1], a1i = aim[r1];
                are[r0] = m00r * a0r - m00i * a0i + m01r * a1r - m01i * a1i;
                aim[r0] = m00r * a0i + m00i * a0r + m01r * a1i + m01i * a1r;
                are[r1] = m10r * a0r - m10i * a0i + m11r * a1r - m11i * a1i;
                aim[r1] = m10r * a0i + m10i * a0r + m11r * a1i + m11i * a1r;
            }
        }
        // lane-bit Rot gates (qubits 4..9, lane bit 9-w) via shfl_xor butterflies
#pragma unroll
        for (int w = 4; w < 10; ++w) {
            const float* g = gate[gbase + w];
            const int lb = 9 - w;
            const int side = (lane >> lb) & 1;
            float cmr = side ? g[6] : g[0];
            float cmi = side ? g[7] : g[1];
            float cpr = side ? g[4] : g[2];
            float cpi = side ? g[5] : g[3];
#pragma unroll
            for (int r = 0; r < 16; ++r) {
                float pr = __shfl_xor(are[r], 1 << lb, 64);
                float pi = __shfl_xor(aim[r], 1 << lb, 64);
                float nr = cmr * are[r] - cmi * aim[r] + cpr * pr - cpi * pi;
                float ni = cmr * aim[r] + cmi * are[r] + cpr * pi + cpi * pr;
                are[r] = nr; aim[r] = ni;
            }
        }

        // ---- CNOT ring, fully in-register (movement order = gate order i=0..9) ----
        // 1. RR: ctrl q=c (reg bit 3-c), tgt q=c+rs<4 (reg bit 3-c-rs): compile-time swaps
#pragma unroll
        for (int c = 0; c < 4; ++c) {
            if (c + rs < 4) {
                const int cb = 3 - c, tm = 1 << (3 - c - rs);
#pragma unroll
                for (int r = 0; r < 16; ++r) {
                    if (((r >> cb) & 1) && !(r & tm)) {
                        float tr_ = are[r]; are[r] = are[r | tm]; are[r | tm] = tr_;
                        float ti_ = aim[r]; aim[r] = aim[r | tm]; aim[r | tm] = ti_;
                    }
                }
            }
        }
        // 2. RL: ctrl reg bit 3-c, tgt lane bit 9-c-rs: per-register constant shfl_xor
#pragma unroll
        for (int r = 0; r < 16; ++r) {
            int m = 0;
#pragma unroll
            for (int c = 0; c < 4; ++c)
                if (c + rs >= 4 && ((r >> (3 - c)) & 1)) m |= 1 << (9 - c - rs);
            if (m) {
                are[r] = __shfl_xor(are[r], m, 64);
                aim[r] = __shfl_xor(aim[r], m, 64);
            }
        }
        // 3. LL: CNOTs i=4..9-rs compose into one lane permutation; source lane
        //    computed by applying the maps in reverse order, then one bpermute pass.
        {
            int y = lane;
#pragma unroll
            for (int i = 9 - rs; i >= 4; --i)
                y ^= ((y >> (9 - i)) & 1) << (9 - i - rs);
            const int addr = y << 2;
#pragma unroll
            for (int r = 0; r < 16; ++r) {
                are[r] = __int_as_float(__builtin_amdgcn_ds_bpermute(addr, __float_as_int(are[r])));
                aim[r] = __int_as_float(__builtin_amdgcn_ds_bpermute(addr, __float_as_int(aim[r])));
            }
        }
        // 4. LR: ctrl lane bit 9-i, tgt reg bit 13-i-rs: predicated register-pair swaps
#pragma unroll
        for (int i = 10 - rs; i <= 9; ++i) {
            const bool p = (lane >> (9 - i)) & 1;
            const int tm = 1 << (13 - i - rs);
#pragma unroll
            for (int r = 0; r < 16; ++r) {
                if (!(r & tm)) {
                    float v0r = are[r], v1r = are[r | tm];
                    are[r] = p ? v1r : v0r;  are[r | tm] = p ? v0r : v1r;
                    float v0i = aim[r], v1i = aim[r | tm];
                    aim[r] = p ? v1i : v0i;  aim[r | tm] = p ? v0i : v1i;
                }
            }
        }
    }

    // Z expectations: e[w] = sum_s |amp|^2 * (1-2*bit_{9-w}(s))
    float p[16], ptot = 0.f;
#pragma unroll
    for (int r = 0; r < 16; ++r) { p[r] = are[r] * are[r] + aim[r] * aim[r]; ptot += p[r]; }
    float e[NQ];
#pragma unroll
    for (int w = 0; w < 4; ++w) {
        float ss = 0.f;
        const int mask = 1 << (3 - w);
#pragma unroll
        for (int r = 0; r < 16; ++r) if (r & mask) ss += p[r];
        e[w] = ptot - 2.f * ss;
    }
#pragma unroll
    for (int w = 4; w < 10; ++w)
        e[w] = ((lane >> (9 - w)) & 1) ? -ptot : ptot;
#pragma unroll
    for (int off = 1; off < 64; off <<= 1) {
#pragma unroll
        for (int w = 0; w < NQ; ++w) e[w] += __shfl_xor(e[w], off, 64);
    }

    // head: out = relu(q@W3^T+b3) @ W4^T + b4   (2 columns per lane + butterfly)
    float accv = 0.f;
#pragma unroll
    for (int j = 0; j < 2; ++j) {
        int c = lane + 64 * j;
        float d = b3s[c];
#pragma unroll
        for (int k = 0; k < NQ; ++k) d = fmaf(w3s[c * 11 + k], e[k], d);
        d = fmaxf(d, 0.f);
        accv = fmaf(d, w4s[c], accv);
    }
#pragma unroll
    for (int off = 1; off < 64; off <<= 1) accv += __shfl_xor(accv, off, 64);
    if (lane == 0) out[row] = accv + b4s;
}

extern "C" void kernel_launch(void* const* d_in, const int* in_sizes, int n_in,
                              void* d_out, int out_size, void* d_ws, size_t ws_size,
                              hipStream_t stream) {
    const float* x  = (const float*)d_in[0];
    const float* W1 = (const float*)d_in[1];
    const float* b1 = (const float*)d_in[2];
    const float* W2 = (const float*)d_in[3];
    const float* b2 = (const float*)d_in[4];
    const float* qw = (const float*)d_in[5];
    const float* W3 = (const float*)d_in[6];
    const float* b3 = (const float*)d_in[7];
    const float* W4 = (const float*)d_in[8];
    const float* b4 = (const float*)d_in[9];
    float* angles = (float*)d_ws;          // 16384 x 10 fp32 scratch
    float* out = (float*)d_out;

    angles_kernel<<<BATCH / 64, 256, 0, stream>>>(x, W1, b1, W2, b2, angles);
    circuit_kernel<<<BATCH / 4, 256, 0, stream>>>(angles, qw, W3, b3, W4, b4, out);
}

// Round 3
// 256.775 us; speedup vs baseline: 1.5472x; 1.2039x over previous
//
#include <hip/hip_runtime.h>
#include <math.h>

#define BATCH 16384
#define INFEAT 256
#define HID 128
#define NQ 10
#define NL 4

// ---------- cross-lane xor helper: DPP for 1,2,3,8; ds_swizzle for <32; shfl for 32+ ----------
template<int M>
__device__ __forceinline__ float lxor(float x) {
    if constexpr (M == 0) {
        return x;
    } else if constexpr (M < 4) {
        constexpr int ctrl = (0 ^ M) | ((1 ^ M) << 2) | ((2 ^ M) << 4) | ((3 ^ M) << 6);
        return __int_as_float(__builtin_amdgcn_update_dpp(
            __float_as_int(x), __float_as_int(x), ctrl, 0xF, 0xF, false));
    } else if constexpr (M == 8) {
        // ROW_ROR:8 within rows of 16 == lane^8
        return __int_as_float(__builtin_amdgcn_update_dpp(
            __float_as_int(x), __float_as_int(x), 0x128, 0xF, 0xF, false));
    } else if constexpr (M < 32) {
        return __int_as_float(__builtin_amdgcn_ds_swizzle(
            __float_as_int(x), (M << 10) | 0x1F));
    } else {
        return __shfl_xor(x, M, 64);
    }
}

// ---------------- Kernel A: angles = tanh(relu(x@W1^T+b1)@W2^T+b2), BM=32 ----------------
__global__ __launch_bounds__(256) void angles_kernel(
    const float* __restrict__ x, const float* __restrict__ W1,
    const float* __restrict__ b1, const float* __restrict__ W2,
    const float* __restrict__ b2, float* __restrict__ angles)
{
    __shared__ float smem[5504];
    float* xst = smem;                 // k-major x tile: [32 k][32 rows], stride 34
    float* wt  = smem + 1088;          // k-major W1 tile: [32 k][128 cols], stride 132
    const int t = threadIdx.x;
    const int tr = t & 15, tc = t >> 4;
    const int row0 = blockIdx.x * 32;

    float b1v[8];
#pragma unroll
    for (int j = 0; j < 8; ++j) b1v[j] = b1[tc * 8 + j];

    float acc[2][8];
#pragma unroll
    for (int i = 0; i < 2; ++i)
#pragma unroll
        for (int j = 0; j < 8; ++j) acc[i][j] = 0.f;

    for (int k0 = 0; k0 < INFEAT; k0 += 32) {
        __syncthreads();
        // stage x tile transposed to k-major (1 float4 per thread, scatter 4 writes)
        {
            int i = t >> 3, j4 = t & 7;
            float4 v = *(const float4*)(x + (size_t)(row0 + i) * INFEAT + k0 + j4 * 4);
            xst[(j4 * 4 + 0) * 34 + i] = v.x;
            xst[(j4 * 4 + 1) * 34 + i] = v.y;
            xst[(j4 * 4 + 2) * 34 + i] = v.z;
            xst[(j4 * 4 + 3) * 34 + i] = v.w;
        }
        // stage W1 tile transposed to k-major: 128 cols x 32 k
        for (int f = t; f < 1024; f += 256) {
            int c = f >> 3, j4 = f & 7;
            float4 v = *(const float4*)(W1 + (size_t)c * INFEAT + k0 + j4 * 4);
            wt[(j4 * 4 + 0) * 132 + c] = v.x;
            wt[(j4 * 4 + 1) * 132 + c] = v.y;
            wt[(j4 * 4 + 2) * 132 + c] = v.z;
            wt[(j4 * 4 + 3) * 132 + c] = v.w;
        }
        __syncthreads();
#pragma unroll 4
        for (int k = 0; k < 32; ++k) {
            float2 xv = *(const float2*)(xst + k * 34 + tr * 2);
            float4 wa = *(const float4*)(wt + k * 132 + tc * 8);
            float4 wb = *(const float4*)(wt + k * 132 + tc * 8 + 4);
            float wv[8] = {wa.x, wa.y, wa.z, wa.w, wb.x, wb.y, wb.z, wb.w};
#pragma unroll
            for (int j = 0; j < 8; ++j) {
                acc[0][j] = fmaf(xv.x, wv[j], acc[0][j]);
                acc[1][j] = fmaf(xv.y, wv[j], acc[1][j]);
            }
        }
    }
    __syncthreads();
    // stage 2: h tile -> LDS, then angles = tanh(h@W2^T + b2)
    float* hbuf = smem;            // 32 x 130
    float* w2s  = smem + 4160;     // 10 x 130
    float* b2s  = smem + 5460;     // 10
    for (int f = t; f < HID * NQ; f += 256) {
        int k = f >> 7, c = f & 127;
        w2s[k * 130 + c] = W2[f];
    }
    if (t < NQ) b2s[t] = b2[t];
#pragma unroll
    for (int i = 0; i < 2; ++i)
#pragma unroll
        for (int j = 0; j < 8; ++j)
            hbuf[(tr * 2 + i) * 130 + tc * 8 + j] = fmaxf(acc[i][j] + b1v[j], 0.f);
    __syncthreads();
    for (int f = t; f < 32 * NQ; f += 256) {
        int row = f / 10;
        int k = f - row * 10;
        float s = b2s[k];
        const float* hr = hbuf + row * 130;
        const float* wr = w2s + k * 130;
#pragma unroll 8
        for (int c = 0; c < HID; ++c) s = fmaf(hr[c], wr[c], s);
        angles[(size_t)(row0 + row) * NQ + k] = tanhf(s);
    }
}

// ---------------- prep: 40 Rot gate matrices -> global table (for scalar loads) ----------------
__global__ void prep_kernel(const float* __restrict__ qw, float* __restrict__ gtab) {
    int t = threadIdx.x;
    if (t < NL * NQ) {
        float phi = qw[t * 3 + 0], th = qw[t * 3 + 1], om = qw[t * 3 + 2];
        float c = __cosf(th * 0.5f), s = __sinf(th * 0.5f);
        float a = 0.5f * (phi + om), b = 0.5f * (phi - om);
        float ca = __cosf(a), sa = __sinf(a);
        float cb = __cosf(b), sb = __sinf(b);
        float* g = gtab + t * 8;
        g[0] = ca * c;  g[1] = -sa * c;   // m00
        g[2] = -cb * s; g[3] = -sb * s;   // m01
        g[4] = cb * s;  g[5] = -sb * s;   // m10
        g[6] = ca * c;  g[7] = sa * c;    // m11
    }
}

// lane-bit Rot gate on lane bit LB (qubit 9-LB) — partner via lxor (DPP/swizzle/shfl)
template<int LB>
__device__ __forceinline__ void lane_gate(const float* __restrict__ g, int lane,
                                          float (&are)[16], float (&aim)[16]) {
    const bool side = (lane >> LB) & 1;
    const float cmr = side ? g[6] : g[0];
    const float cmi = side ? g[7] : g[1];
    const float cpr = side ? g[4] : g[2];
    const float cpi = side ? g[5] : g[3];
#pragma unroll
    for (int r = 0; r < 16; ++r) {
        float pr = lxor<(1 << LB)>(are[r]);
        float pi = lxor<(1 << LB)>(aim[r]);
        float nr = cmr * are[r] - cmi * aim[r] + cpr * pr - cpi * pi;
        float ni = cmr * aim[r] + cmi * are[r] + cpr * pi + cpi * pr;
        are[r] = nr; aim[r] = ni;
    }
}

// RL CNOT pass: regs with reg-bit CB set get lanes xor'd by M
template<int CB, int M>
__device__ __forceinline__ void rl_pass(float (&are)[16], float (&aim)[16]) {
#pragma unroll
    for (int r = 0; r < 16; ++r) {
        if ((r >> CB) & 1) {
            are[r] = lxor<M>(are[r]);
            aim[r] = lxor<M>(aim[r]);
        }
    }
}

// ---------------- Kernel B: circuit + head, one wave per batch row ----------------
// State: index s = r*64 + lane; qubit w <-> bit (9-w) of s (qubits 0..3 reg bits, 4..9 lane bits).
__global__ __launch_bounds__(256) void circuit_kernel(
    const float* __restrict__ angles, const float* __restrict__ gtab,
    const float* __restrict__ W3, const float* __restrict__ b3,
    const float* __restrict__ W4, const float* __restrict__ b4,
    float* __restrict__ out)
{
    __shared__ float w3s[HID * 11];
    __shared__ float b3s[HID], w4s[HID];
    __shared__ float b4s;

    const int t = threadIdx.x;
    for (int f = t; f < HID * NQ; f += 256) {
        int c = f / NQ, k = f - c * NQ;
        w3s[c * 11 + k] = W3[f];
    }
    if (t < HID) { b3s[t] = b3[t]; w4s[t] = W4[t]; }
    if (t == 0) b4s = b4[0];
    __syncthreads();

    const int lane = t & 63;
    const int row = blockIdx.x * 4 + (t >> 6);

    float cth[NQ], sth[NQ];
#pragma unroll
    for (int w = 0; w < NQ; ++w) {
        float th = angles[(size_t)row * NQ + w] * 0.5f;
        cth[w] = __cosf(th); sth[w] = __sinf(th);
    }

    // RY ladder on |0..0> is a product state
    float fl = 1.f;
#pragma unroll
    for (int w = 4; w < 10; ++w)
        fl *= ((lane >> (9 - w)) & 1) ? sth[w] : cth[w];
    float are[16], aim[16];
#pragma unroll
    for (int r = 0; r < 16; ++r) {
        float g = fl;
#pragma unroll
        for (int w = 0; w < 4; ++w)
            g *= ((r >> (3 - w)) & 1) ? sth[w] : cth[w];
        are[r] = g; aim[r] = 0.f;
    }

#pragma unroll
    for (int l = 0; l < NL; ++l) {
        const int gbase = l * NQ;
        const int rs = l + 1;
        // reg-bit Rot gates (qubits 0..3)
#pragma unroll
        for (int w = 0; w < 4; ++w) {
            const float* __restrict__ g = gtab + (gbase + w) * 8;
            float m00r = g[0], m00i = g[1], m01r = g[2], m01i = g[3];
            float m10r = g[4], m10i = g[5], m11r = g[6], m11i = g[7];
            const int mask = 1 << (3 - w);
#pragma unroll
            for (int r0 = 0; r0 < 16; ++r0) {
                if (r0 & mask) continue;
                const int r1 = r0 | mask;
                float a0r = are[r0], a0i = aim[r0], a1r = are[r1], a1i = aim[r1];
                are[r0] = m00r * a0r - m00i * a0i + m01r * a1r - m01i * a1i;
                aim[r0] = m00r * a0i + m00i * a0r + m01r * a1i + m01i * a1r;
                are[r1] = m10r * a0r - m10i * a0i + m11r * a1r - m11i * a1i;
                aim[r1] = m10r * a0i + m10i * a0r + m11r * a1i + m11i * a1r;
            }
        }
        // lane-bit Rot gates (qubits 4..9 <-> lane bits 5..0)
        lane_gate<5>(gtab + (gbase + 4) * 8, lane, are, aim);
        lane_gate<4>(gtab + (gbase + 5) * 8, lane, are, aim);
        lane_gate<3>(gtab + (gbase + 6) * 8, lane, are, aim);
        lane_gate<2>(gtab + (gbase + 7) * 8, lane, are, aim);
        lane_gate<1>(gtab + (gbase + 8) * 8, lane, are, aim);
        lane_gate<0>(gtab + (gbase + 9) * 8, lane, are, aim);

        // ---- CNOT ring (ascending gate order = RR, RL, LL, LR) ----
        // RR: compile-time register swaps
#pragma unroll
        for (int c = 0; c < 4; ++c) {
            if (c + rs < 4) {
                const int cb = 3 - c, tm = 1 << (3 - c - rs);
#pragma unroll
                for (int r = 0; r < 16; ++r) {
                    if (((r >> cb) & 1) && !(r & tm)) {
                        float tr_ = are[r]; are[r] = are[r | tm]; are[r | tm] = tr_;
                        float ti_ = aim[r]; aim[r] = aim[r | tm]; aim[r | tm] = ti_;
                    }
                }
            }
        }
        // RL: single-bit passes (ctrl reg bit 3-c -> lane bit 9-c-rs)
        if (l == 0) {
            rl_pass<0, 32>(are, aim);
        } else if (l == 1) {
            rl_pass<1, 32>(are, aim);
            rl_pass<0, 16>(are, aim);
        } else if (l == 2) {
            rl_pass<2, 32>(are, aim);
            rl_pass<1, 16>(are, aim);
            rl_pass<0, 8>(are, aim);
        } else {
            rl_pass<3, 32>(are, aim);
            rl_pass<2, 16>(are, aim);
            rl_pass<1, 8>(are, aim);
            rl_pass<0, 4>(are, aim);
        }
        // LL: composed lane permutation via one bpermute pass
        {
            int y = lane;
#pragma unroll
            for (int i = 9 - rs; i >= 4; --i)
                y ^= ((y >> (9 - i)) & 1) << (9 - i - rs);
            const int addr = y << 2;
#pragma unroll
            for (int r = 0; r < 16; ++r) {
                are[r] = __int_as_float(__builtin_amdgcn_ds_bpermute(addr, __float_as_int(are[r])));
                aim[r] = __int_as_float(__builtin_amdgcn_ds_bpermute(addr, __float_as_int(aim[r])));
            }
        }
        // LR: ctrl lane bit 9-i, tgt reg bit 13-i-rs: predicated register-pair swaps
#pragma unroll
        for (int i = 10 - rs; i <= 9; ++i) {
            const bool p = (lane >> (9 - i)) & 1;
            const int tm = 1 << (13 - i - rs);
#pragma unroll
            for (int r = 0; r < 16; ++r) {
                if (!(r & tm)) {
                    float v0r = are[r], v1r = are[r | tm];
                    are[r] = p ? v1r : v0r;  are[r | tm] = p ? v0r : v1r;
                    float v0i = aim[r], v1i = aim[r | tm];
                    aim[r] = p ? v1i : v0i;  aim[r | tm] = p ? v0i : v1i;
                }
            }
        }
    }

    // Z expectations
    float p[16], ptot = 0.f;
#pragma unroll
    for (int r = 0; r < 16; ++r) { p[r] = are[r] * are[r] + aim[r] * aim[r]; ptot += p[r]; }
    float e[NQ];
#pragma unroll
    for (int w = 0; w < 4; ++w) {
        float ss = 0.f;
        const int mask = 1 << (3 - w);
#pragma unroll
        for (int r = 0; r < 16; ++r) if (r & mask) ss += p[r];
        e[w] = ptot - 2.f * ss;
    }
#pragma unroll
    for (int w = 4; w < 10; ++w)
        e[w] = ((lane >> (9 - w)) & 1) ? -ptot : ptot;
    // all-reduce each e across 64 lanes (DPP for 1,2,8; swizzle 4,16; shfl 32)
#pragma unroll
    for (int w = 0; w < NQ; ++w) {
        e[w] += lxor<1>(e[w]);
        e[w] += lxor<2>(e[w]);
        e[w] += lxor<8>(e[w]);
        e[w] += lxor<4>(e[w]);
        e[w] += lxor<16>(e[w]);
        e[w] += lxor<32>(e[w]);
    }

    // head: out = relu(q@W3^T+b3) @ W4^T + b4
    float accv = 0.f;
#pragma unroll
    for (int j = 0; j < 2; ++j) {
        int c = lane + 64 * j;
        float d = b3s[c];
#pragma unroll
        for (int k = 0; k < NQ; ++k) d = fmaf(w3s[c * 11 + k], e[k], d);
        d = fmaxf(d, 0.f);
        accv = fmaf(d, w4s[c], accv);
    }
    accv += lxor<1>(accv);
    accv += lxor<2>(accv);
    accv += lxor<8>(accv);
    accv += lxor<4>(accv);
    accv += lxor<16>(accv);
    accv += lxor<32>(accv);
    if (lane == 0) out[row] = accv + b4s;
}

extern "C" void kernel_launch(void* const* d_in, const int* in_sizes, int n_in,
                              void* d_out, int out_size, void* d_ws, size_t ws_size,
                              hipStream_t stream) {
    const float* x  = (const float*)d_in[0];
    const float* W1 = (const float*)d_in[1];
    const float* b1 = (const float*)d_in[2];
    const float* W2 = (const float*)d_in[3];
    const float* b2 = (const float*)d_in[4];
    const float* qw = (const float*)d_in[5];
    const float* W3 = (const float*)d_in[6];
    const float* b3 = (const float*)d_in[7];
    const float* W4 = (const float*)d_in[8];
    const float* b4 = (const float*)d_in[9];
    float* angles = (float*)d_ws;                       // BATCH*NQ floats
    float* gtab   = (float*)d_ws + (size_t)BATCH * NQ;  // 320 floats
    float* out = (float*)d_out;

    prep_kernel<<<1, 64, 0, stream>>>(qw, gtab);
    angles_kernel<<<BATCH / 32, 256, 0, stream>>>(x, W1, b1, W2, b2, angles);
    circuit_kernel<<<BATCH / 4, 256, 0, stream>>>(angles, gtab, W3, b3, W4, b4, out);
}